// Round 2
// baseline (3274.456 us; speedup 1.0000x reference)
//
#include <hip/hip_runtime.h>
#include <hip/hip_bf16.h>
#include <math.h>

#define B_ 64
#define N_ 197
#define C_ 768
#define H_ 12
#define D_ 64
#define BN_ (B_ * N_)  // 12608

typedef unsigned short ushort_t;

__device__ __forceinline__ float wave_reduce_sum(float v) {
#pragma unroll
  for (int off = 32; off; off >>= 1) v += __shfl_xor(v, off);
  return v;
}
__device__ __forceinline__ float wave_reduce_max(float v) {
#pragma unroll
  for (int off = 32; off; off >>= 1) v = fmaxf(v, __shfl_xor(v, off));
  return v;
}

__device__ __forceinline__ ushort_t f2bf(float f) {
  __hip_bfloat16 h = __float2bfloat16(f);
  ushort_t u;
  __builtin_memcpy(&u, &h, 2);
  return u;
}
__device__ __forceinline__ float bflo(unsigned u) { return __uint_as_float(u << 16); }
__device__ __forceinline__ float bfhi(unsigned u) { return __uint_as_float(u & 0xFFFF0000u); }
__device__ __forceinline__ float bfu(ushort_t u) { return __uint_as_float((unsigned)u << 16); }

// ---------------- LayerNorm: one block per row (C=768 = 256*3) ----------------
__global__ __launch_bounds__(256) void ln_kernel(const float* __restrict__ x,
                                                 const float* __restrict__ w,
                                                 const float* __restrict__ bsh,
                                                 float* __restrict__ out) {
  const int row = blockIdx.x;
  const float* xr = x + (size_t)row * C_;
  const int tid = threadIdx.x;
  float v0 = xr[tid], v1 = xr[tid + 256], v2 = xr[tid + 512];
  float s = v0 + v1 + v2;
  float q = v0 * v0 + v1 * v1 + v2 * v2;
  s = wave_reduce_sum(s);
  q = wave_reduce_sum(q);
  __shared__ float red[8];
  const int w4 = tid >> 6, l = tid & 63;
  if (l == 0) { red[w4] = s; red[4 + w4] = q; }
  __syncthreads();
  float ts = red[0] + red[1] + red[2] + red[3];
  float tq = red[4] + red[5] + red[6] + red[7];
  float mu = ts * (1.f / C_);
  float var = tq * (1.f / C_) - mu * mu;
  float rs = rsqrtf(var + 1e-5f);
  float* orow = out + (size_t)row * C_;
  orow[tid]       = (v0 - mu) * rs * w[tid]       + bsh[tid];
  orow[tid + 256] = (v1 - mu) * rs * w[tid + 256] + bsh[tid + 256];
  orow[tid + 512] = (v2 - mu) * rs * w[tid + 512] + bsh[tid + 512];
}

// ---------------- fp32 GEMM: C = A(MxK) * B(KxN) + bias [+res] [gelu] --------
// 64x64 tile, BK=16, 256 threads, 4x4 per thread. All dims divisible.
template <int RES, int ACT>
__global__ __launch_bounds__(256) void gemm_kernel(const float* __restrict__ A,
                                                   const float* __restrict__ Bw,
                                                   const float* __restrict__ bias,
                                                   const float* __restrict__ res,
                                                   float* __restrict__ Cmat,
                                                   int M, int Nc, int K) {
  __shared__ __align__(16) float As[16][68];  // [k][m], pad 68 for alignment + conflicts
  __shared__ __align__(16) float Bs[16][64];  // [k][n]
  const int tid = threadIdx.x;
  const int tx = tid & 15, ty = tid >> 4;
  const int bm = blockIdx.y * 64, bnn = blockIdx.x * 64;
  float acc[4][4] = {};
  const int am = tid >> 2, ak = (tid & 3) * 4;
  const int bk = tid >> 4, bn = (tid & 15) * 4;
  const float* Aptr = A + (size_t)(bm + am) * K + ak;
  const float* Bptr = Bw + (size_t)bk * Nc + bnn + bn;
  for (int k0 = 0; k0 < K; k0 += 16) {
    float4 av = *(const float4*)(Aptr + k0);
    As[ak + 0][am] = av.x;
    As[ak + 1][am] = av.y;
    As[ak + 2][am] = av.z;
    As[ak + 3][am] = av.w;
    float4 bv = *(const float4*)(Bptr + (size_t)k0 * Nc);
    *(float4*)&Bs[bk][bn] = bv;
    __syncthreads();
#pragma unroll
    for (int kk = 0; kk < 16; kk++) {
      float4 a4 = *(const float4*)&As[kk][ty * 4];
      float4 b4 = *(const float4*)&Bs[kk][tx * 4];
      float a[4] = {a4.x, a4.y, a4.z, a4.w};
      float b[4] = {b4.x, b4.y, b4.z, b4.w};
#pragma unroll
      for (int i = 0; i < 4; i++)
#pragma unroll
        for (int j = 0; j < 4; j++) acc[i][j] = fmaf(a[i], b[j], acc[i][j]);
    }
    __syncthreads();
  }
#pragma unroll
  for (int i = 0; i < 4; i++) {
    const int row = bm + ty * 4 + i;
    float4 o;
    float vv[4];
#pragma unroll
    for (int j = 0; j < 4; j++) {
      const int col = bnn + tx * 4 + j;
      float v = acc[i][j] + bias[col];
      if constexpr (RES) v += res[(size_t)row * Nc + col];
      if constexpr (ACT) v = 0.5f * v * (1.f + erff(v * 0.70710678118654752f));
      vv[j] = v;
    }
    o.x = vv[0]; o.y = vv[1]; o.z = vv[2]; o.w = vv[3];
    *(float4*)&Cmat[(size_t)row * Nc + bnn + tx * 4] = o;
  }
}

// ---------------- Attention: one block per (b,h) -----------------------------
// K,V staged in LDS as bf16. Score stage: lane l owns key columns {4l..4l+3},
// shuffle-broadcast q[d]. Softmax with wave reductions. PV stage: lane l owns
// output dim d = l (one dim per lane); shuffle-broadcast p_j.
__global__ __launch_bounds__(256) void attn_kernel(const float* __restrict__ qkv,
                                                   const float* __restrict__ mask,
                                                   float* __restrict__ aout,
                                                   float* __restrict__ imp) {
  const int b = blockIdx.x / H_, h = blockIdx.x % H_;
  __shared__ __align__(16) ushort_t Kt[64][200];  // [d][j] bf16, zero-padded j>=197
  __shared__ __align__(16) ushort_t Vs[200][64];  // [j][d] bf16, zero-padded
  const int tid = threadIdx.x, w = tid >> 6, l = tid & 63;
  const float* base = qkv + (size_t)b * N_ * 2304 + h * 64;
  // K at +768, V at +1536 (qkv row layout: [s*768 + h*64 + d], row stride 2304)
  for (int idx = tid; idx < 200 * 64; idx += 256) {
    const int j = idx >> 6, d = idx & 63;
    float kv = 0.f, vv = 0.f;
    if (j < N_) {
      kv = base[768 + (size_t)j * 2304 + d];
      vv = base[1536 + (size_t)j * 2304 + d];
    }
    Kt[d][j] = f2bf(kv);
    Vs[j][d] = f2bf(vv);
  }
  __syncthreads();
  float mk[4];
#pragma unroll
  for (int u = 0; u < 4; u++) {
    const int j = 4 * l + u;
    mk[u] = (j < N_) ? mask[b * N_ + j] : 0.f;
  }
  float cs[4] = {0.f, 0.f, 0.f, 0.f};
  for (int i = w; i < N_; i += 4) {
    const float qreg = base[(size_t)i * 2304 + l];  // q[d = l]
    float s0 = 0.f, s1 = 0.f, s2 = 0.f, s3 = 0.f;
    const bool in_range = (4 * l < 200 - 3);  // guard LDS row OOB for l>=50
#pragma unroll
    for (int d = 0; d < 64; d++) {
      const float qd = __shfl(qreg, d);
      const uint2 kw = in_range ? *(const uint2*)&Kt[d][4 * (l < 50 ? l : 0)]
                                : make_uint2(0u, 0u);
      s0 = fmaf(qd, bflo(kw.x), s0);
      s1 = fmaf(qd, bfhi(kw.x), s1);
      s2 = fmaf(qd, bflo(kw.y), s2);
      s3 = fmaf(qd, bfhi(kw.y), s3);
    }
    const float SC = 0.125f;  // D^-0.5
    float sa[4] = {s0 * SC, s1 * SC, s2 * SC, s3 * SC};
    float mx = -INFINITY;
#pragma unroll
    for (int u = 0; u < 4; u++)
      if (4 * l + u < N_) mx = fmaxf(mx, sa[u]);
    mx = wave_reduce_max(mx);
    float e[4];
    float sum = 0.f;
#pragma unroll
    for (int u = 0; u < 4; u++) {
      e[u] = (4 * l + u < N_) ? __expf(sa[u] - mx) * mk[u] : 0.f;
      sum += e[u];
    }
    sum = wave_reduce_sum(sum);
    const float inv = 1.f / (sum + 1e-6f);
    const float p0 = e[0] * inv, p1 = e[1] * inv, p2 = e[2] * inv, p3 = e[3] * inv;
    cs[0] += p0; cs[1] += p1; cs[2] += p2; cs[3] += p3;
    // PV: lane l computes output dim d = l. p_j for j=4*jb+u lives on lane jb
    // in register p_u. Vs zero-padded for j>=197 and p==0 there.
    float o = 0.f;
    for (int jb = 0; jb < 50; jb++) {
      const float pj0 = __shfl(p0, jb);
      const float pj1 = __shfl(p1, jb);
      const float pj2 = __shfl(p2, jb);
      const float pj3 = __shfl(p3, jb);
      const int j = 4 * jb;
      o = fmaf(pj0, bfu(Vs[j + 0][l]), o);
      o = fmaf(pj1, bfu(Vs[j + 1][l]), o);
      o = fmaf(pj2, bfu(Vs[j + 2][l]), o);
      o = fmaf(pj3, bfu(Vs[j + 3][l]), o);
    }
    aout[(size_t)(b * N_ + i) * C_ + h * 64 + l] = o;
  }
#pragma unroll
  for (int u = 0; u < 4; u++) {
    const int j = 4 * l + u;
    if (j < N_) atomicAdd(&imp[b * N_ + j], cs[u] * (1.f / (H_ * (float)N_)));
  }
}

// ---------------- mask output ------------------------------------------------
__global__ __launch_bounds__(256) void mask_kernel(const float* __restrict__ imp,
                                                   const float* __restrict__ mask,
                                                   const float* __restrict__ thr,
                                                   float* __restrict__ mask_out) {
  const int i = blockIdx.x * 256 + threadIdx.x;
  if (i >= BN_) return;
  const int n = i % N_;
  const float iv = (n == 0) ? INFINITY : imp[i];
  const float m = mask[i];
  const float nm = (iv > thr[0]) ? 1.f : 0.f;
  mask_out[i] = (m > 0.f) ? nm : m;
}

extern "C" void kernel_launch(void* const* d_in, const int* in_sizes, int n_in,
                              void* d_out, int out_size, void* d_ws, size_t ws_size,
                              hipStream_t stream) {
  const float* x      = (const float*)d_in[0];
  const float* mask   = (const float*)d_in[1];
  const float* ln1_w  = (const float*)d_in[2];
  const float* ln1_b  = (const float*)d_in[3];
  const float* qkv_w  = (const float*)d_in[4];
  const float* qkv_b  = (const float*)d_in[5];
  const float* proj_w = (const float*)d_in[6];
  const float* proj_b = (const float*)d_in[7];
  const float* ln2_w  = (const float*)d_in[8];
  const float* ln2_b  = (const float*)d_in[9];
  const float* fc1_w  = (const float*)d_in[10];
  const float* fc1_b  = (const float*)d_in[11];
  const float* fc2_w  = (const float*)d_in[12];
  const float* fc2_b  = (const float*)d_in[13];
  const float* thr    = (const float*)d_in[14];

  float* out = (float*)d_out;                       // x result: BN_*C_ floats
  float* mask_out = out + (size_t)BN_ * C_;         // then BN_ floats

  // workspace layout (fp32):
  //   bufA: max(qkv, fc1out) = BN_*3072
  //   hbuf: BN_*768  (LN out; reused as attention out after qkv GEMM)
  //   impb: BN_
  float* bufA = (float*)d_ws;
  float* hbuf = bufA + (size_t)BN_ * 3072;
  float* impb = hbuf + (size_t)BN_ * 768;

  hipMemsetAsync(impb, 0, BN_ * sizeof(float), stream);

  // 1) h = LN1(x)
  ln_kernel<<<BN_, 256, 0, stream>>>(x, ln1_w, ln1_b, hbuf);
  // 2) qkv = h @ qkv_w + qkv_b   (12608 x 2304 x 768)
  gemm_kernel<0, 0><<<dim3(2304 / 64, BN_ / 64), 256, 0, stream>>>(
      hbuf, qkv_w, qkv_b, nullptr, bufA, BN_, 2304, 768);
  // 3) attention (writes attn-out into hbuf region, imp atomics)
  attn_kernel<<<B_ * H_, 256, 0, stream>>>(bufA, mask, hbuf, impb);
  // 4) mask output
  mask_kernel<<<(BN_ + 255) / 256, 256, 0, stream>>>(impb, mask, thr, mask_out);
  // 5) x1 = attn_out @ proj_w + proj_b + x   -> d_out
  gemm_kernel<1, 0><<<dim3(768 / 64, BN_ / 64), 256, 0, stream>>>(
      hbuf, proj_w, proj_b, x, out, BN_, 768, 768);
  // 6) h2 = LN2(x1)
  ln_kernel<<<BN_, 256, 0, stream>>>(out, ln2_w, ln2_b, hbuf);
  // 7) f1 = gelu(h2 @ fc1_w + fc1_b)  (12608 x 3072 x 768)
  gemm_kernel<0, 1><<<dim3(3072 / 64, BN_ / 64), 256, 0, stream>>>(
      hbuf, fc1_w, fc1_b, nullptr, bufA, BN_, 3072, 768);
  // 8) x_out = f1 @ fc2_w + fc2_b + x1  (12608 x 768 x 3072) -> d_out in place
  gemm_kernel<1, 0><<<dim3(768 / 64, BN_ / 64), 256, 0, stream>>>(
      bufA, fc2_w, fc2_b, out, out, BN_, 768, 3072);
}

// Round 3
// 1252.817 us; speedup vs baseline: 2.6137x; 2.6137x over previous
//
#include <hip/hip_runtime.h>
#include <hip/hip_bf16.h>
#include <math.h>

#define B_ 64
#define N_ 197
#define C_ 768
#define H_ 12
#define BN_ (B_ * N_)   // 12608
#define MPAD 12672      // 99 * 128  (M padded to tile multiple)

typedef unsigned short ushort_t;
typedef __attribute__((ext_vector_type(8))) short short8;   // 8 x bf16 (4 VGPRs)
typedef __attribute__((ext_vector_type(4))) float f32x4;    // MFMA C/D frag

__device__ __forceinline__ float wave_reduce_sum(float v) {
#pragma unroll
  for (int off = 32; off; off >>= 1) v += __shfl_xor(v, off);
  return v;
}
__device__ __forceinline__ float wave_reduce_max(float v) {
#pragma unroll
  for (int off = 32; off; off >>= 1) v = fmaxf(v, __shfl_xor(v, off));
  return v;
}

__device__ __forceinline__ ushort_t f2bf(float f) {
  __hip_bfloat16 h = __float2bfloat16(f);
  ushort_t u;
  __builtin_memcpy(&u, &h, 2);
  return u;
}
__device__ __forceinline__ float bfu(ushort_t u) { return __uint_as_float((unsigned)u << 16); }

// ---------------- weight convert + transpose: fp32 [K][N] -> bf16 [N][K] -----
__global__ __launch_bounds__(256) void wtrans_kernel(const float* __restrict__ W,
                                                     ushort_t* __restrict__ Wt,
                                                     int K, int N) {
  __shared__ ushort_t tile[32][33];
  const int bn = blockIdx.x * 32, bk = blockIdx.y * 32;
  const int tx = threadIdx.x & 31, ty = threadIdx.x >> 5;  // 32 x 8
#pragma unroll
  for (int i = ty; i < 32; i += 8)
    tile[i][tx] = f2bf(W[(size_t)(bk + i) * N + bn + tx]);
  __syncthreads();
#pragma unroll
  for (int i = ty; i < 32; i += 8)
    Wt[(size_t)(bn + i) * K + bk + tx] = tile[tx][i];
}

// ---------------- LayerNorm -> bf16 out --------------------------------------
__global__ __launch_bounds__(256) void ln_kernel(const float* __restrict__ x,
                                                 const float* __restrict__ w,
                                                 const float* __restrict__ bsh,
                                                 ushort_t* __restrict__ out) {
  const int row = blockIdx.x;
  const float* xr = x + (size_t)row * C_;
  const int tid = threadIdx.x;
  float v0 = xr[tid], v1 = xr[tid + 256], v2 = xr[tid + 512];
  float s = v0 + v1 + v2;
  float q = v0 * v0 + v1 * v1 + v2 * v2;
  s = wave_reduce_sum(s);
  q = wave_reduce_sum(q);
  __shared__ float red[8];
  const int w4 = tid >> 6, l = tid & 63;
  if (l == 0) { red[w4] = s; red[4 + w4] = q; }
  __syncthreads();
  float ts = red[0] + red[1] + red[2] + red[3];
  float tq = red[4] + red[5] + red[6] + red[7];
  float mu = ts * (1.f / C_);
  float var = tq * (1.f / C_) - mu * mu;
  float rs = rsqrtf(var + 1e-5f);
  ushort_t* orow = out + (size_t)row * C_;
  orow[tid]       = f2bf((v0 - mu) * rs * w[tid]       + bsh[tid]);
  orow[tid + 256] = f2bf((v1 - mu) * rs * w[tid + 256] + bsh[tid + 256]);
  orow[tid + 512] = f2bf((v2 - mu) * rs * w[tid + 512] + bsh[tid + 512]);
}

// ---------------- bf16 MFMA GEMM: C = A(MxK) * Bt(NxK)^T + bias --------------
// 128x128 tile, BK=32, 256 threads (4 waves, 2x2 of 64x64), 16x16x32 MFMA.
// A, Bt bf16 row-major; staging via global_load_lds width=16 (m97 structure).
template <int RES, int ACT, int OUT_BF16>
__global__ __launch_bounds__(256) void mfma_gemm(const ushort_t* __restrict__ A,
                                                 const ushort_t* __restrict__ Bt,
                                                 const float* __restrict__ bias,
                                                 const float* __restrict__ res,
                                                 void* __restrict__ Cout,
                                                 int M, int Nc, int K) {
  __shared__ __align__(16) ushort_t As[128][32];  // [m][k], 64 B rows
  __shared__ __align__(16) ushort_t Bs[128][32];  // [n][k]
  const int tid = threadIdx.x;
  const int w = tid >> 6, l = tid & 63;
  const int bm = blockIdx.y * 128, bnn = blockIdx.x * 128;
  const int quad = l >> 4, lm = l & 15;
  const int wm = (w >> 1) * 64, wn = (w & 1) * 64;

  // Staging: 8 KB per operand = 8 chunks of 1024 B (16 rows). Wave w stages
  // chunks {2w, 2w+1} of both A and B. Lane l: row = chunk*16 + l/4,
  // k-elems (l%4)*8 .. +7. LDS dest = wave-uniform base + lane*16 (HW rule).
  const int c0 = w * 2, c1 = w * 2 + 1;
  const int srow = l >> 2, scol = (l & 3) << 3;
  const ushort_t* ag0 = A + (size_t)(bm + c0 * 16 + srow) * K + scol;
  const ushort_t* ag1 = A + (size_t)(bm + c1 * 16 + srow) * K + scol;
  const ushort_t* bg0 = Bt + (size_t)(bnn + c0 * 16 + srow) * K + scol;
  const ushort_t* bg1 = Bt + (size_t)(bnn + c1 * 16 + srow) * K + scol;
  ushort_t* la0 = &As[c0 * 16][0];
  ushort_t* la1 = &As[c1 * 16][0];
  ushort_t* lb0 = &Bs[c0 * 16][0];
  ushort_t* lb1 = &Bs[c1 * 16][0];

  f32x4 acc[4][4];
#pragma unroll
  for (int mi = 0; mi < 4; mi++)
#pragma unroll
    for (int ni = 0; ni < 4; ni++) acc[mi][ni] = (f32x4){0.f, 0.f, 0.f, 0.f};

  for (int k0 = 0; k0 < K; k0 += 32) {
    __builtin_amdgcn_global_load_lds(
        (const __attribute__((address_space(1))) void*)(ag0 + k0),
        (__attribute__((address_space(3))) void*)la0, 16, 0, 0);
    __builtin_amdgcn_global_load_lds(
        (const __attribute__((address_space(1))) void*)(ag1 + k0),
        (__attribute__((address_space(3))) void*)la1, 16, 0, 0);
    __builtin_amdgcn_global_load_lds(
        (const __attribute__((address_space(1))) void*)(bg0 + k0),
        (__attribute__((address_space(3))) void*)lb0, 16, 0, 0);
    __builtin_amdgcn_global_load_lds(
        (const __attribute__((address_space(1))) void*)(bg1 + k0),
        (__attribute__((address_space(3))) void*)lb1, 16, 0, 0);
    __syncthreads();  // drains vmcnt before any wave reads the tile

    short8 af[4], bf[4];
#pragma unroll
    for (int i = 0; i < 4; i++) {
      af[i] = *(const short8*)&As[wm + i * 16 + lm][quad * 8];
      bf[i] = *(const short8*)&Bs[wn + i * 16 + lm][quad * 8];
    }
#pragma unroll
    for (int mi = 0; mi < 4; mi++)
#pragma unroll
      for (int ni = 0; ni < 4; ni++)
        acc[mi][ni] = __builtin_amdgcn_mfma_f32_16x16x32_bf16(
            af[mi], bf[ni], acc[mi][ni], 0, 0, 0);
    __syncthreads();  // tile consumed; safe to overwrite next iter
  }

  // Epilogue: C/D layout col=lane&15, row=quad*4+reg (m89/m91 verified).
#pragma unroll
  for (int mi = 0; mi < 4; mi++) {
#pragma unroll
    for (int ni = 0; ni < 4; ni++) {
      const int col = bnn + wn + ni * 16 + lm;
      const float bv = bias[col];
#pragma unroll
      for (int r = 0; r < 4; r++) {
        const int row = bm + wm + mi * 16 + quad * 4 + r;
        if (row < M) {
          float v = acc[mi][ni][r] + bv;
          if constexpr (RES) v += res[(size_t)row * Nc + col];
          if constexpr (ACT) v = 0.5f * v * (1.f + erff(v * 0.70710678118654752f));
          if constexpr (OUT_BF16)
            ((ushort_t*)Cout)[(size_t)row * Nc + col] = f2bf(v);
          else
            ((float*)Cout)[(size_t)row * Nc + col] = v;
        }
      }
    }
  }
}

// ---------------- Attention: one block per (b,h), qkv/out in bf16 ------------
__global__ __launch_bounds__(256) void attn_kernel(const ushort_t* __restrict__ qkv,
                                                   const float* __restrict__ mask,
                                                   ushort_t* __restrict__ aout,
                                                   float* __restrict__ imp) {
  const int b = blockIdx.x / H_, h = blockIdx.x % H_;
  __shared__ __align__(16) ushort_t Kt[64][200];  // [d][j], zero-padded j>=197
  __shared__ __align__(16) ushort_t Vs[200][64];  // [j][d], zero-padded
  const int tid = threadIdx.x, w = tid >> 6, l = tid & 63;
  const ushort_t* base = qkv + (size_t)b * N_ * 2304 + h * 64;
  for (int idx = tid; idx < 200 * 64; idx += 256) {
    const int j = idx >> 6, d = idx & 63;
    ushort_t kv = 0, vv = 0;
    if (j < N_) {
      kv = base[768 + (size_t)j * 2304 + d];
      vv = base[1536 + (size_t)j * 2304 + d];
    }
    Kt[d][j] = kv;
    Vs[j][d] = vv;
  }
  __syncthreads();
  float mk[4];
#pragma unroll
  for (int u = 0; u < 4; u++) {
    const int j = 4 * l + u;
    mk[u] = (j < N_) ? mask[b * N_ + j] : 0.f;
  }
  float cs[4] = {0.f, 0.f, 0.f, 0.f};
  for (int i = w; i < N_; i += 4) {
    const float qreg = bfu(base[(size_t)i * 2304 + l]);  // q[d = l]
    float s0 = 0.f, s1 = 0.f, s2 = 0.f, s3 = 0.f;
    const bool in_range = (4 * l < 200 - 3);  // LDS row-OOB guard for l>=50
#pragma unroll
    for (int d = 0; d < 64; d++) {
      const float qd = __shfl(qreg, d);
      const uint2 kw = in_range ? *(const uint2*)&Kt[d][4 * (l < 50 ? l : 0)]
                                : make_uint2(0u, 0u);
      s0 = fmaf(qd, __uint_as_float(kw.x << 16), s0);
      s1 = fmaf(qd, __uint_as_float(kw.x & 0xFFFF0000u), s1);
      s2 = fmaf(qd, __uint_as_float(kw.y << 16), s2);
      s3 = fmaf(qd, __uint_as_float(kw.y & 0xFFFF0000u), s3);
    }
    const float SC = 0.125f;
    float sa[4] = {s0 * SC, s1 * SC, s2 * SC, s3 * SC};
    float mx = -INFINITY;
#pragma unroll
    for (int u = 0; u < 4; u++)
      if (4 * l + u < N_) mx = fmaxf(mx, sa[u]);
    mx = wave_reduce_max(mx);
    float e[4];
    float sum = 0.f;
#pragma unroll
    for (int u = 0; u < 4; u++) {
      e[u] = (4 * l + u < N_) ? __expf(sa[u] - mx) * mk[u] : 0.f;
      sum += e[u];
    }
    sum = wave_reduce_sum(sum);
    const float inv = 1.f / (sum + 1e-6f);
    const float p0 = e[0] * inv, p1 = e[1] * inv, p2 = e[2] * inv, p3 = e[3] * inv;
    cs[0] += p0; cs[1] += p1; cs[2] += p2; cs[3] += p3;
    float o = 0.f;  // lane l owns output dim d = l
    for (int jb = 0; jb < 50; jb++) {
      const float pj0 = __shfl(p0, jb);
      const float pj1 = __shfl(p1, jb);
      const float pj2 = __shfl(p2, jb);
      const float pj3 = __shfl(p3, jb);
      const int j = 4 * jb;
      o = fmaf(pj0, bfu(Vs[j + 0][l]), o);
      o = fmaf(pj1, bfu(Vs[j + 1][l]), o);
      o = fmaf(pj2, bfu(Vs[j + 2][l]), o);
      o = fmaf(pj3, bfu(Vs[j + 3][l]), o);
    }
    aout[(size_t)(b * N_ + i) * C_ + h * 64 + l] = f2bf(o);
  }
#pragma unroll
  for (int u = 0; u < 4; u++) {
    const int j = 4 * l + u;
    if (j < N_) atomicAdd(&imp[b * N_ + j], cs[u] * (1.f / (H_ * (float)N_)));
  }
}

// ---------------- mask output ------------------------------------------------
__global__ __launch_bounds__(256) void mask_kernel(const float* __restrict__ imp,
                                                   const float* __restrict__ mask,
                                                   const float* __restrict__ thr,
                                                   float* __restrict__ mask_out) {
  const int i = blockIdx.x * 256 + threadIdx.x;
  if (i >= BN_) return;
  const int n = i % N_;
  const float iv = (n == 0) ? INFINITY : imp[i];
  const float m = mask[i];
  const float nm = (iv > thr[0]) ? 1.f : 0.f;
  mask_out[i] = (m > 0.f) ? nm : m;
}

extern "C" void kernel_launch(void* const* d_in, const int* in_sizes, int n_in,
                              void* d_out, int out_size, void* d_ws, size_t ws_size,
                              hipStream_t stream) {
  const float* x      = (const float*)d_in[0];
  const float* mask   = (const float*)d_in[1];
  const float* ln1_w  = (const float*)d_in[2];
  const float* ln1_b  = (const float*)d_in[3];
  const float* qkv_w  = (const float*)d_in[4];
  const float* qkv_b  = (const float*)d_in[5];
  const float* proj_w = (const float*)d_in[6];
  const float* proj_b = (const float*)d_in[7];
  const float* ln2_w  = (const float*)d_in[8];
  const float* ln2_b  = (const float*)d_in[9];
  const float* fc1_w  = (const float*)d_in[10];
  const float* fc1_b  = (const float*)d_in[11];
  const float* fc2_w  = (const float*)d_in[12];
  const float* fc2_b  = (const float*)d_in[13];
  const float* thr    = (const float*)d_in[14];

  float* out = (float*)d_out;                // x result: BN_*C_ fp32
  float* mask_out = out + (size_t)BN_ * C_;  // then BN_ fp32

  // workspace (bf16 elements unless noted); M-padded buffers to MPAD rows.
  ushort_t* buf0    = (ushort_t*)d_ws;                   // qkv out / fc1 out (aliased)
  ushort_t* hbuf    = buf0 + (size_t)MPAD * 3072;        // LN out
  ushort_t* aoutb   = hbuf + (size_t)MPAD * 768;         // attention out
  ushort_t* qkv_wt  = aoutb + (size_t)MPAD * 768;        // 2304x768
  ushort_t* proj_wt = qkv_wt + (size_t)2304 * 768;       // 768x768
  ushort_t* fc1_wt  = proj_wt + (size_t)768 * 768;       // 3072x768
  ushort_t* fc2_wt  = fc1_wt + (size_t)3072 * 768;       // 768x3072
  float*    impb    = (float*)(fc2_wt + (size_t)768 * 3072);

  hipMemsetAsync(impb, 0, BN_ * sizeof(float), stream);

  // 0) weight convert+transpose fp32[K][N] -> bf16[N][K]
  wtrans_kernel<<<dim3(2304 / 32, 768 / 32), 256, 0, stream>>>(qkv_w, qkv_wt, 768, 2304);
  wtrans_kernel<<<dim3(768 / 32, 768 / 32), 256, 0, stream>>>(proj_w, proj_wt, 768, 768);
  wtrans_kernel<<<dim3(3072 / 32, 768 / 32), 256, 0, stream>>>(fc1_w, fc1_wt, 768, 3072);
  wtrans_kernel<<<dim3(768 / 32, 3072 / 32), 256, 0, stream>>>(fc2_w, fc2_wt, 3072, 768);

  const int gy = MPAD / 128;  // 99 M-tiles
  // 1) h = LN1(x) -> bf16
  ln_kernel<<<BN_, 256, 0, stream>>>(x, ln1_w, ln1_b, hbuf);
  // 2) qkv = h @ qkv_w + qkv_b -> bf16
  mfma_gemm<0, 0, 1><<<dim3(2304 / 128, gy), 256, 0, stream>>>(
      hbuf, qkv_wt, qkv_b, nullptr, buf0, BN_, 2304, 768);
  // 3) attention
  attn_kernel<<<B_ * H_, 256, 0, stream>>>(buf0, mask, aoutb, impb);
  // 4) mask output
  mask_kernel<<<(BN_ + 255) / 256, 256, 0, stream>>>(impb, mask, thr, mask_out);
  // 5) x1 = attn_out @ proj_w + proj_b + x -> d_out (fp32)
  mfma_gemm<1, 0, 0><<<dim3(768 / 128, gy), 256, 0, stream>>>(
      aoutb, proj_wt, proj_b, x, out, BN_, 768, 768);
  // 6) h2 = LN2(x1) -> bf16
  ln_kernel<<<BN_, 256, 0, stream>>>(out, ln2_w, ln2_b, hbuf);
  // 7) f1 = gelu(h2 @ fc1_w + fc1_b) -> bf16
  mfma_gemm<0, 1, 1><<<dim3(3072 / 128, gy), 256, 0, stream>>>(
      hbuf, fc1_wt, fc1_b, nullptr, buf0, BN_, 3072, 768);
  // 8) x_out = f1 @ fc2_w + fc2_b + x1 -> d_out (fp32, in-place residual)
  mfma_gemm<1, 0, 0><<<dim3(768 / 128, gy), 256, 0, stream>>>(
      buf0, fc2_wt, fc2_b, out, out, BN_, 768, 3072);
}

// Round 4
// 607.164 us; speedup vs baseline: 5.3930x; 2.0634x over previous
//
#include <hip/hip_runtime.h>
#include <hip/hip_bf16.h>
#include <math.h>

#define B_ 64
#define N_ 197
#define C_ 768
#define H_ 12
#define BN_ (B_ * N_)   // 12608
#define MPAD 12672      // 99 * 128  (M padded to tile multiple)

typedef unsigned short ushort_t;
typedef __attribute__((ext_vector_type(8))) short short8;   // 8 x bf16 (4 VGPRs)
typedef __attribute__((ext_vector_type(4))) float f32x4;    // MFMA C/D frag

__device__ __forceinline__ float wave_reduce_sum(float v) {
#pragma unroll
  for (int off = 32; off; off >>= 1) v += __shfl_xor(v, off);
  return v;
}

__device__ __forceinline__ ushort_t f2bf(float f) {
  __hip_bfloat16 h = __float2bfloat16(f);
  ushort_t u;
  __builtin_memcpy(&u, &h, 2);
  return u;
}

// ---------------- weight convert + transpose: fp32 [K][N] -> bf16 [N][K] -----
__global__ __launch_bounds__(256) void wtrans_kernel(const float* __restrict__ W,
                                                     ushort_t* __restrict__ Wt,
                                                     int K, int N) {
  __shared__ ushort_t tile[32][33];
  const int bn = blockIdx.x * 32, bk = blockIdx.y * 32;
  const int tx = threadIdx.x & 31, ty = threadIdx.x >> 5;  // 32 x 8
#pragma unroll
  for (int i = ty; i < 32; i += 8)
    tile[i][tx] = f2bf(W[(size_t)(bk + i) * N + bn + tx]);
  __syncthreads();
#pragma unroll
  for (int i = ty; i < 32; i += 8)
    Wt[(size_t)(bn + i) * K + bk + tx] = tile[tx][i];
}

// ---------------- LayerNorm -> bf16 out --------------------------------------
__global__ __launch_bounds__(256) void ln_kernel(const float* __restrict__ x,
                                                 const float* __restrict__ w,
                                                 const float* __restrict__ bsh,
                                                 ushort_t* __restrict__ out) {
  const int row = blockIdx.x;
  const float* xr = x + (size_t)row * C_;
  const int tid = threadIdx.x;
  float v0 = xr[tid], v1 = xr[tid + 256], v2 = xr[tid + 512];
  float s = v0 + v1 + v2;
  float q = v0 * v0 + v1 * v1 + v2 * v2;
  s = wave_reduce_sum(s);
  q = wave_reduce_sum(q);
  __shared__ float red[8];
  const int w4 = tid >> 6, l = tid & 63;
  if (l == 0) { red[w4] = s; red[4 + w4] = q; }
  __syncthreads();
  float ts = red[0] + red[1] + red[2] + red[3];
  float tq = red[4] + red[5] + red[6] + red[7];
  float mu = ts * (1.f / C_);
  float var = tq * (1.f / C_) - mu * mu;
  float rs = rsqrtf(var + 1e-5f);
  ushort_t* orow = out + (size_t)row * C_;
  orow[tid]       = f2bf((v0 - mu) * rs * w[tid]       + bsh[tid]);
  orow[tid + 256] = f2bf((v1 - mu) * rs * w[tid + 256] + bsh[tid + 256]);
  orow[tid + 512] = f2bf((v2 - mu) * rs * w[tid + 512] + bsh[tid + 512]);
}

// ---------------- bf16 MFMA GEMM: C = A(MxK) * Bt(NxK)^T + bias --------------
// 128x128 tile, BK=32, 256 threads (4 waves, 2x2 of 64x64), 16x16x32 MFMA.
template <int RES, int ACT, int OUT_BF16>
__global__ __launch_bounds__(256) void mfma_gemm(const ushort_t* __restrict__ A,
                                                 const ushort_t* __restrict__ Bt,
                                                 const float* __restrict__ bias,
                                                 const float* __restrict__ res,
                                                 void* __restrict__ Cout,
                                                 int M, int Nc, int K) {
  __shared__ __align__(16) ushort_t As[128][32];  // [m][k], 64 B rows
  __shared__ __align__(16) ushort_t Bs[128][32];  // [n][k]
  const int tid = threadIdx.x;
  const int w = tid >> 6, l = tid & 63;
  const int bm = blockIdx.y * 128, bnn = blockIdx.x * 128;
  const int quad = l >> 4, lm = l & 15;
  const int wm = (w >> 1) * 64, wn = (w & 1) * 64;

  const int c0 = w * 2, c1 = w * 2 + 1;
  const int srow = l >> 2, scol = (l & 3) << 3;
  const ushort_t* ag0 = A + (size_t)(bm + c0 * 16 + srow) * K + scol;
  const ushort_t* ag1 = A + (size_t)(bm + c1 * 16 + srow) * K + scol;
  const ushort_t* bg0 = Bt + (size_t)(bnn + c0 * 16 + srow) * K + scol;
  const ushort_t* bg1 = Bt + (size_t)(bnn + c1 * 16 + srow) * K + scol;
  ushort_t* la0 = &As[c0 * 16][0];
  ushort_t* la1 = &As[c1 * 16][0];
  ushort_t* lb0 = &Bs[c0 * 16][0];
  ushort_t* lb1 = &Bs[c1 * 16][0];

  f32x4 acc[4][4];
#pragma unroll
  for (int mi = 0; mi < 4; mi++)
#pragma unroll
    for (int ni = 0; ni < 4; ni++) acc[mi][ni] = (f32x4){0.f, 0.f, 0.f, 0.f};

  for (int k0 = 0; k0 < K; k0 += 32) {
    __builtin_amdgcn_global_load_lds(
        (const __attribute__((address_space(1))) void*)(ag0 + k0),
        (__attribute__((address_space(3))) void*)la0, 16, 0, 0);
    __builtin_amdgcn_global_load_lds(
        (const __attribute__((address_space(1))) void*)(ag1 + k0),
        (__attribute__((address_space(3))) void*)la1, 16, 0, 0);
    __builtin_amdgcn_global_load_lds(
        (const __attribute__((address_space(1))) void*)(bg0 + k0),
        (__attribute__((address_space(3))) void*)lb0, 16, 0, 0);
    __builtin_amdgcn_global_load_lds(
        (const __attribute__((address_space(1))) void*)(bg1 + k0),
        (__attribute__((address_space(3))) void*)lb1, 16, 0, 0);
    __syncthreads();

    short8 af[4], bf[4];
#pragma unroll
    for (int i = 0; i < 4; i++) {
      af[i] = *(const short8*)&As[wm + i * 16 + lm][quad * 8];
      bf[i] = *(const short8*)&Bs[wn + i * 16 + lm][quad * 8];
    }
#pragma unroll
    for (int mi = 0; mi < 4; mi++)
#pragma unroll
      for (int ni = 0; ni < 4; ni++)
        acc[mi][ni] = __builtin_amdgcn_mfma_f32_16x16x32_bf16(
            af[mi], bf[ni], acc[mi][ni], 0, 0, 0);
    __syncthreads();
  }

#pragma unroll
  for (int mi = 0; mi < 4; mi++) {
#pragma unroll
    for (int ni = 0; ni < 4; ni++) {
      const int col = bnn + wn + ni * 16 + lm;
      const float bv = bias[col];
#pragma unroll
      for (int r = 0; r < 4; r++) {
        const int row = bm + wm + mi * 16 + quad * 4 + r;
        if (row < M) {
          float v = acc[mi][ni][r] + bv;
          if constexpr (RES) v += res[(size_t)row * Nc + col];
          if constexpr (ACT) v = 0.5f * v * (1.f + erff(v * 0.70710678118654752f));
          if constexpr (OUT_BF16)
            ((ushort_t*)Cout)[(size_t)row * Nc + col] = f2bf(v);
          else
            ((float*)Cout)[(size_t)row * Nc + col] = v;
        }
      }
    }
  }
}

// ---------------- MFMA attention: one block per (b,h) ------------------------
// LDS: Ks (keys, swizzled for conflict-free B-frag reads), Vt (V transposed),
// Pb (per-wave P strip for the C-layout -> A-layout round-trip).
// Each wave owns 16-row Q-tiles (i0 = w*16 + 64*t). Keys padded to 208; K rows
// >=197 zeroed, mask zeroes their softmax weight. PV k-tail (192..207) uses a
// 16x16x32 mfma with the upper 16 k zeroed via exec-masked frag loads.
__global__ __launch_bounds__(256, 2) void attn_mfma(const ushort_t* __restrict__ qkv,
                                                    const float* __restrict__ mask,
                                                    ushort_t* __restrict__ aout,
                                                    float* __restrict__ imp) {
  __shared__ __align__(16) ushort_t Ks[208 * 64];     // (j, g^(j&7)) swizzle, 26624 B
  __shared__ __align__(16) ushort_t Vt[64 * 216];     // [d][j], 27648 B
  __shared__ __align__(16) ushort_t Pb[4][16 * 208];  // per-wave, 26624 B
  const int b = blockIdx.x / H_, h = blockIdx.x % H_;
  const int tid = threadIdx.x, w = tid >> 6, l = tid & 63;
  const int quad = l >> 4, lm = l & 15;
  const ushort_t* qbase = qkv + (size_t)b * N_ * 2304 + h * 64;
  const ushort_t* kbase = qbase + 768;
  const ushort_t* vbase = qbase + 1536;

  // stage K: item (j, g) = 16B; swizzled slot g^(j&7) so B-frag reads are
  // 2-way-max on banks (free per m136).
  for (int idx = tid; idx < 208 * 8; idx += 256) {
    const int j = idx >> 3, g = idx & 7;
    uint4 val = make_uint4(0u, 0u, 0u, 0u);
    if (j < N_) val = *(const uint4*)(kbase + (size_t)j * 2304 + g * 8);
    *(uint4*)&Ks[j * 64 + ((g ^ (j & 7)) << 3)] = val;
  }
  // stage V transposed: item (jg, d): read V[4jg..4jg+3][d], write Vt[d][4jg..]
  for (int idx = tid; idx < 52 * 64; idx += 256) {
    const int d = idx & 63, jg = idx >> 6, j0 = jg * 4;
    ushort_t a0 = 0, a1 = 0, a2 = 0, a3 = 0;
    if (j0 + 0 < N_) a0 = vbase[(size_t)(j0 + 0) * 2304 + d];
    if (j0 + 1 < N_) a1 = vbase[(size_t)(j0 + 1) * 2304 + d];
    if (j0 + 2 < N_) a2 = vbase[(size_t)(j0 + 2) * 2304 + d];
    if (j0 + 3 < N_) a3 = vbase[(size_t)(j0 + 3) * 2304 + d];
    uint2 pk;
    pk.x = (unsigned)a0 | ((unsigned)a1 << 16);
    pk.y = (unsigned)a2 | ((unsigned)a3 << 16);
    *(uint2*)&Vt[d * 216 + j0] = pk;
  }
  float mkv[13];
#pragma unroll
  for (int t = 0; t < 13; t++) {
    const int col = t * 16 + lm;
    mkv[t] = (col < N_) ? mask[b * N_ + col] : 0.f;
  }
  float cs[13];
#pragma unroll
  for (int t = 0; t < 13; t++) cs[t] = 0.f;
  __syncthreads();

  ushort_t* pw = &Pb[w][0];
  for (int i0 = w * 16; i0 < 208; i0 += 64) {  // ragged per-wave Q-tiles; no barriers inside
    f32x4 accs[13];
#pragma unroll
    for (int t = 0; t < 13; t++) accs[t] = (f32x4){0.f, 0.f, 0.f, 0.f};
    // S = Q K^T  (A-frag from global, B-frag from swizzled LDS)
#pragma unroll
    for (int kh = 0; kh < 2; kh++) {
      const int k0 = kh * 32;
      const short8 aq =
          *(const short8*)(qbase + (size_t)(i0 + lm) * 2304 + k0 + quad * 8);
      const int gb = (k0 >> 3) + quad;
#pragma unroll
      for (int t = 0; t < 13; t++) {
        const int j = t * 16 + lm;
        const short8 bk = *(const short8*)&Ks[j * 64 + ((gb ^ (j & 7)) << 3)];
        accs[t] = __builtin_amdgcn_mfma_f32_16x16x32_bf16(aq, bk, accs[t], 0, 0, 0);
      }
    }
    // softmax (C-layout: row = quad*4+r spread over lm lanes within the quad)
    float inv[4];
#pragma unroll
    for (int r = 0; r < 4; r++) {
      float m = -3.4e38f;
#pragma unroll
      for (int t = 0; t < 13; t++) m = fmaxf(m, accs[t][r] * 0.125f);
      m = fmaxf(m, __shfl_xor(m, 1));
      m = fmaxf(m, __shfl_xor(m, 2));
      m = fmaxf(m, __shfl_xor(m, 4));
      m = fmaxf(m, __shfl_xor(m, 8));
      float s = 0.f;
#pragma unroll
      for (int t = 0; t < 13; t++) {
        const float e = __expf(accs[t][r] * 0.125f - m) * mkv[t];
        accs[t][r] = e;
        s += e;
      }
      s += __shfl_xor(s, 1);
      s += __shfl_xor(s, 2);
      s += __shfl_xor(s, 4);
      s += __shfl_xor(s, 8);
      inv[r] = 1.f / (s + 1e-6f);
    }
    const int ibase = i0 + quad * 4;
#pragma unroll
    for (int r = 0; r < 4; r++) {
      const bool rok = (ibase + r) < N_;  // exclude padded/garbage query rows from imp
#pragma unroll
      for (int t = 0; t < 13; t++) {
        const float p = accs[t][r] * inv[r];
        accs[t][r] = p;
        if (rok) cs[t] += p;
        pw[(quad * 4 + r) * 208 + t * 16 + lm] = f2bf(p);
      }
    }
    __builtin_amdgcn_wave_barrier();  // pin ds_write(P) before ds_read(P); LDS is in-order per wave
    // O = P V  (A = P strip, B = Vt)
    f32x4 acco[4];
#pragma unroll
    for (int n = 0; n < 4; n++) acco[n] = (f32x4){0.f, 0.f, 0.f, 0.f};
#pragma unroll
    for (int ks = 0; ks < 6; ks++) {
      const int k0 = ks * 32;
      const short8 ap = *(const short8*)&pw[lm * 208 + k0 + quad * 8];
#pragma unroll
      for (int n = 0; n < 4; n++) {
        const short8 bv = *(const short8*)&Vt[(n * 16 + lm) * 216 + k0 + quad * 8];
        acco[n] = __builtin_amdgcn_mfma_f32_16x16x32_bf16(ap, bv, acco[n], 0, 0, 0);
      }
    }
    {  // k-tail 192..207: upper half (k 208..223) zeroed via exec-masked loads
      const bool lo = (quad < 2);
      short8 apt = {};
      if (lo) apt = *(const short8*)&pw[lm * 208 + 192 + quad * 8];
#pragma unroll
      for (int n = 0; n < 4; n++) {
        short8 bvt = {};
        if (lo) bvt = *(const short8*)&Vt[(n * 16 + lm) * 216 + 192 + quad * 8];
        acco[n] = __builtin_amdgcn_mfma_f32_16x16x32_bf16(apt, bvt, acco[n], 0, 0, 0);
      }
    }
#pragma unroll
    for (int r = 0; r < 4; r++) {
      const int i = ibase + r;
      if (i < N_) {
#pragma unroll
        for (int n = 0; n < 4; n++)
          aout[(size_t)(b * N_ + i) * C_ + h * 64 + n * 16 + lm] = f2bf(acco[n][r]);
      }
    }
  }
  // imp column sums: reduce the 4 quads (row groups), one atomic per (col, wave)
#pragma unroll
  for (int t = 0; t < 13; t++) {
    float v = cs[t];
    v += __shfl_xor(v, 16);
    v += __shfl_xor(v, 32);
    if (l < 16) {
      const int col = t * 16 + l;
      if (col < N_)
        atomicAdd(&imp[b * N_ + col], v * (1.f / (H_ * (float)N_)));
    }
  }
}

// ---------------- mask output ------------------------------------------------
__global__ __launch_bounds__(256) void mask_kernel(const float* __restrict__ imp,
                                                   const float* __restrict__ mask,
                                                   const float* __restrict__ thr,
                                                   float* __restrict__ mask_out) {
  const int i = blockIdx.x * 256 + threadIdx.x;
  if (i >= BN_) return;
  const int n = i % N_;
  const float iv = (n == 0) ? INFINITY : imp[i];
  const float m = mask[i];
  const float nm = (iv > thr[0]) ? 1.f : 0.f;
  mask_out[i] = (m > 0.f) ? nm : m;
}

extern "C" void kernel_launch(void* const* d_in, const int* in_sizes, int n_in,
                              void* d_out, int out_size, void* d_ws, size_t ws_size,
                              hipStream_t stream) {
  const float* x      = (const float*)d_in[0];
  const float* mask   = (const float*)d_in[1];
  const float* ln1_w  = (const float*)d_in[2];
  const float* ln1_b  = (const float*)d_in[3];
  const float* qkv_w  = (const float*)d_in[4];
  const float* qkv_b  = (const float*)d_in[5];
  const float* proj_w = (const float*)d_in[6];
  const float* proj_b = (const float*)d_in[7];
  const float* ln2_w  = (const float*)d_in[8];
  const float* ln2_b  = (const float*)d_in[9];
  const float* fc1_w  = (const float*)d_in[10];
  const float* fc1_b  = (const float*)d_in[11];
  const float* fc2_w  = (const float*)d_in[12];
  const float* fc2_b  = (const float*)d_in[13];
  const float* thr    = (const float*)d_in[14];

  float* out = (float*)d_out;                // x result: BN_*C_ fp32
  float* mask_out = out + (size_t)BN_ * C_;  // then BN_ fp32

  ushort_t* buf0    = (ushort_t*)d_ws;                   // qkv out / fc1 out (aliased)
  ushort_t* hbuf    = buf0 + (size_t)MPAD * 3072;        // LN out
  ushort_t* aoutb   = hbuf + (size_t)MPAD * 768;         // attention out
  ushort_t* qkv_wt  = aoutb + (size_t)MPAD * 768;        // 2304x768
  ushort_t* proj_wt = qkv_wt + (size_t)2304 * 768;       // 768x768
  ushort_t* fc1_wt  = proj_wt + (size_t)768 * 768;       // 3072x768
  ushort_t* fc2_wt  = fc1_wt + (size_t)3072 * 768;       // 768x3072
  float*    impb    = (float*)(fc2_wt + (size_t)768 * 3072);

  hipMemsetAsync(impb, 0, BN_ * sizeof(float), stream);

  wtrans_kernel<<<dim3(2304 / 32, 768 / 32), 256, 0, stream>>>(qkv_w, qkv_wt, 768, 2304);
  wtrans_kernel<<<dim3(768 / 32, 768 / 32), 256, 0, stream>>>(proj_w, proj_wt, 768, 768);
  wtrans_kernel<<<dim3(3072 / 32, 768 / 32), 256, 0, stream>>>(fc1_w, fc1_wt, 768, 3072);
  wtrans_kernel<<<dim3(768 / 32, 3072 / 32), 256, 0, stream>>>(fc2_w, fc2_wt, 3072, 768);

  const int gy = MPAD / 128;  // 99 M-tiles
  ln_kernel<<<BN_, 256, 0, stream>>>(x, ln1_w, ln1_b, hbuf);
  mfma_gemm<0, 0, 1><<<dim3(2304 / 128, gy), 256, 0, stream>>>(
      hbuf, qkv_wt, qkv_b, nullptr, buf0, BN_, 2304, 768);
  attn_mfma<<<B_ * H_, 256, 0, stream>>>(buf0, mask, aoutb, impb);
  mask_kernel<<<(BN_ + 255) / 256, 256, 0, stream>>>(impb, mask, thr, mask_out);
  mfma_gemm<1, 0, 0><<<dim3(768 / 128, gy), 256, 0, stream>>>(
      aoutb, proj_wt, proj_b, x, out, BN_, 768, 768);
  ln_kernel<<<BN_, 256, 0, stream>>>(out, ln2_w, ln2_b, hbuf);
  mfma_gemm<0, 1, 1><<<dim3(3072 / 128, gy), 256, 0, stream>>>(
      hbuf, fc1_wt, fc1_b, nullptr, buf0, BN_, 3072, 768);
  mfma_gemm<1, 0, 0><<<dim3(768 / 128, gy), 256, 0, stream>>>(
      buf0, fc2_wt, fc2_b, out, out, BN_, 768, 3072);
}